// Round 1
// baseline (390.721 us; speedup 1.0000x reference)
//
#include <hip/hip_runtime.h>

using short8 = __attribute__((ext_vector_type(8))) short;
using f32x4  = __attribute__((ext_vector_type(4))) float;

#define SCALE 0.15811388300841897f  // 40^-0.5

__device__ __forceinline__ unsigned short f2bf(float f) {
  unsigned int u = __float_as_uint(f);
  u += 0x7fffu + ((u >> 16) & 1u);   // RNE (inputs finite)
  return (unsigned short)(u >> 16);
}

// ---------------- ws layout (ushort units) ----------------
// wqt: [320][320]  Wqt[n][k] = bf16(Wq[k][n]*SCALE)   @ 0        (102400)
// wot: [320][320]  Wot[n][k] = bf16(Wo[k][n])         @ 102400   (102400)
// kbf: [16][8][80][64]  K padded (m->80, d->64, zeros) @ 204800   (655360)
// vt : [16][8][48][96]  V^T padded (d->48, m->96)      @ 860160   (589824)

// ============ kernel 0: weight transpose + bf16 ============
__global__ void prep_weights(const float* __restrict__ Wq, const float* __restrict__ Wo,
                             unsigned short* __restrict__ wqt, unsigned short* __restrict__ wot) {
  int id = blockIdx.x * 256 + threadIdx.x;      // grid 800*256 = 204800 exactly
  if (id < 102400) {
    int n = id / 320, k = id - n * 320;
    wqt[id] = f2bf(Wq[k * 320 + n] * SCALE);
  } else {
    int id2 = id - 102400;
    int n = id2 / 320, k = id2 - n * 320;
    wot[id2] = f2bf(Wo[k * 320 + n]);
  }
}

// ============ kernel 1: K,V projection (f32 tiled) ============
// grid (16, 8, 4), 256 threads
__global__ void kv_kernel(const float* __restrict__ ctx,
                          const float* __restrict__ Wk, const float* __restrict__ Wv,
                          unsigned short* __restrict__ kbf, unsigned short* __restrict__ vt) {
  const int b = blockIdx.x, h = blockIdx.y, z = blockIdx.z;
  const int tid = threadIdx.x;
  __shared__ float sc[24][65];
  __shared__ float sw[64][40];

  // ---- K phase: m = z*20 .. z*20+19, d = 0..63 ----
  {
    const int d  = tid & 63;
    const int m0 = tid >> 6;   // 0..3
    float acc[5] = {0.f, 0.f, 0.f, 0.f, 0.f};
    for (int kc = 0; kc < 768; kc += 64) {
      __syncthreads();
      for (int i = tid; i < 20 * 64; i += 256) {
        int r = i >> 6, c = i & 63;
        int m = z * 20 + r;
        sc[r][c] = (m < 77) ? ctx[(b * 77 + m) * 768 + kc + c] : 0.f;
      }
      for (int i = tid; i < 64 * 40; i += 256) {
        int r = i / 40, c = i - r * 40;
        sw[r][c] = Wk[(kc + r) * 320 + h * 40 + c];
      }
      __syncthreads();
      if (d < 40) {
        for (int c = 0; c < 64; ++c) {
          float w = sw[c][d];
          #pragma unroll
          for (int i = 0; i < 5; ++i) acc[i] += sc[m0 + 4 * i][c] * w;
        }
      }
    }
    #pragma unroll
    for (int i = 0; i < 5; ++i) {
      int m = z * 20 + m0 + 4 * i;
      float v = (d < 40 && m < 77) ? acc[i] : 0.f;
      kbf[((b * 8 + h) * 80 + m) * 64 + d] = f2bf(v);
    }
  }

  // ---- V phase: Vt[d][m], m = z*24 .. +23, d = 0..47 ----
  {
    const int mv = tid & 31;   // only <24 active
    const int d0 = tid >> 5;   // 0..7
    float accv[6] = {0.f, 0.f, 0.f, 0.f, 0.f, 0.f};
    for (int kc = 0; kc < 768; kc += 64) {
      __syncthreads();
      for (int i = tid; i < 24 * 64; i += 256) {
        int r = i >> 6, c = i & 63;
        int m = z * 24 + r;
        sc[r][c] = (m < 77) ? ctx[(b * 77 + m) * 768 + kc + c] : 0.f;
      }
      for (int i = tid; i < 64 * 40; i += 256) {
        int r = i / 40, c = i - r * 40;
        sw[r][c] = Wv[(kc + r) * 320 + h * 40 + c];
      }
      __syncthreads();
      if (mv < 24) {
        for (int c = 0; c < 64; ++c) {
          float a = sc[mv][c];
          #pragma unroll
          for (int i = 0; i < 6; ++i) {
            int dd = d0 + 8 * i;
            accv[i] += a * ((dd < 40) ? sw[c][dd] : 0.f);
          }
        }
      }
    }
    if (mv < 24) {
      #pragma unroll
      for (int i = 0; i < 6; ++i) {
        int dd = d0 + 8 * i;
        int m = z * 24 + mv;
        float v = (dd < 40 && m < 77) ? accv[i] : 0.f;
        vt[((b * 8 + h) * 48 + dd) * 96 + m] = f2bf(v);
      }
    }
  }
}

// ============ kernel 2: fused Q-GEMM + attention + out-proj ============
// grid (64 qtiles, 16 batch), 256 threads (4 waves). Each block: 64 query rows.
__global__ __launch_bounds__(256, 1)
void attn_kernel(const float* __restrict__ x, const float* __restrict__ bo,
                 float* __restrict__ out,
                 const unsigned short* __restrict__ wqt, const unsigned short* __restrict__ wot,
                 const unsigned short* __restrict__ kbf, const unsigned short* __restrict__ vtp) {
  const int b  = blockIdx.y;
  const int q0 = blockIdx.x * 64;
  const int tid = threadIdx.x;
  const int w   = tid >> 6;       // wave 0..3
  const int l   = tid & 63;
  const int l16 = l & 15;
  const int lhi = l >> 4;         // 0..3

  __shared__ __align__(16) unsigned short Qt[64][520];  // per-head 64-wide slots, cols h*64+40..63 zero
  __shared__ __align__(16) unsigned short XO[64][328];  // x tile, then O tile
  __shared__ __align__(16) unsigned short Pt[64][104];  // P (m padded to 96)

  // --- zero Qt (pad cols must be 0), load x tile -> bf16 LDS ---
  {
    uint4* qz = reinterpret_cast<uint4*>(&Qt[0][0]);
    for (int i = tid; i < 64 * 520 * 2 / 16; i += 256) qz[i] = (uint4){0u, 0u, 0u, 0u};
    const float4* xin = reinterpret_cast<const float4*>(x + (size_t)(b * 4096 + q0) * 320);
    for (int i = tid; i < 64 * 80; i += 256) {
      float4 v = xin[i];
      int row = i / 80, c4 = (i - row * 80) * 4;
      ushort4 u;
      u.x = f2bf(v.x); u.y = f2bf(v.y); u.z = f2bf(v.z); u.w = f2bf(v.w);
      *reinterpret_cast<ushort4*>(&XO[row][c4]) = u;
    }
    // zero Pt cols 80..103 once (never rewritten; read as A-operand padding)
    for (int i = tid; i < 64 * 24; i += 256) {
      int row = i / 24, c = 80 + (i - row * 24);
      Pt[row][c] = 0;
    }
  }
  __syncthreads();

  // --- Phase 1: Q = Xt @ Wqt^T  (wave w owns output cols 80w..80w+79) ---
  {
    f32x4 qacc[4][5];
    #pragma unroll
    for (int rt = 0; rt < 4; ++rt)
      #pragma unroll
      for (int nt = 0; nt < 5; ++nt) qacc[rt][nt] = (f32x4){0.f, 0.f, 0.f, 0.f};
    for (int ks = 0; ks < 10; ++ks) {
      short8 afrag[4];
      #pragma unroll
      for (int rt = 0; rt < 4; ++rt)
        afrag[rt] = *reinterpret_cast<const short8*>(&XO[rt * 16 + l16][ks * 32 + lhi * 8]);
      short8 bfrag[5];
      #pragma unroll
      for (int nt = 0; nt < 5; ++nt) {
        int col = w * 80 + nt * 16 + l16;
        bfrag[nt] = *reinterpret_cast<const short8*>(&wqt[col * 320 + ks * 32 + lhi * 8]);
      }
      #pragma unroll
      for (int rt = 0; rt < 4; ++rt)
        #pragma unroll
        for (int nt = 0; nt < 5; ++nt)
          qacc[rt][nt] = __builtin_amdgcn_mfma_f32_16x16x32_bf16(afrag[rt], bfrag[nt], qacc[rt][nt], 0, 0, 0);
    }
    // scatter to Qt (head-blocked layout)
    #pragma unroll
    for (int rt = 0; rt < 4; ++rt)
      #pragma unroll
      for (int nt = 0; nt < 5; ++nt) {
        int c = w * 80 + nt * 16 + l16;   // 0..319
        int h = c / 40, d = c - h * 40;
        #pragma unroll
        for (int r = 0; r < 4; ++r)
          Qt[rt * 16 + lhi * 4 + r][h * 64 + d] = f2bf(qacc[rt][nt][r]);
      }
  }
  __syncthreads();

  // --- Phase 2: per-head attention (wave w owns query rows 16w..16w+15) ---
  for (int h = 0; h < 8; ++h) {
    const unsigned short* kh = kbf + ((size_t)(b * 8 + h) * 80) * 64;
    const unsigned short* vh = vtp + ((size_t)(b * 8 + h) * 48) * 96;
    // S = Q_h @ K_h^T
    f32x4 sacc[5];
    #pragma unroll
    for (int mt = 0; mt < 5; ++mt) sacc[mt] = (f32x4){0.f, 0.f, 0.f, 0.f};
    #pragma unroll
    for (int ks = 0; ks < 2; ++ks) {
      short8 a = *reinterpret_cast<const short8*>(&Qt[w * 16 + l16][h * 64 + ks * 32 + lhi * 8]);
      #pragma unroll
      for (int mt = 0; mt < 5; ++mt) {
        short8 bb = *reinterpret_cast<const short8*>(&kh[(mt * 16 + l16) * 64 + ks * 32 + lhi * 8]);
        sacc[mt] = __builtin_amdgcn_mfma_f32_16x16x32_bf16(a, bb, sacc[mt], 0, 0, 0);
      }
    }
    // softmax (rows distributed: row = 16w + 4*lhi + r; keys across l16 and mt)
    #pragma unroll
    for (int r = 0; r < 4; ++r) {
      float sv[5];
      float mx = -1e30f;
      #pragma unroll
      for (int mt = 0; mt < 5; ++mt) {
        float s = sacc[mt][r];
        if (mt * 16 + l16 >= 77) s = -1e30f;
        sv[mt] = s;
        mx = fmaxf(mx, s);
      }
      mx = fmaxf(mx, __shfl_xor(mx, 1));
      mx = fmaxf(mx, __shfl_xor(mx, 2));
      mx = fmaxf(mx, __shfl_xor(mx, 4));
      mx = fmaxf(mx, __shfl_xor(mx, 8));
      float sum = 0.f;
      #pragma unroll
      for (int mt = 0; mt < 5; ++mt) { sv[mt] = __expf(sv[mt] - mx); sum += sv[mt]; }
      sum += __shfl_xor(sum, 1);
      sum += __shfl_xor(sum, 2);
      sum += __shfl_xor(sum, 4);
      sum += __shfl_xor(sum, 8);
      float rs = 1.f / sum;
      int row = w * 16 + lhi * 4 + r;
      #pragma unroll
      for (int mt = 0; mt < 5; ++mt)
        Pt[row][mt * 16 + l16] = f2bf(sv[mt] * rs);
    }
    __syncthreads();
    // O_h = P @ V_h
    f32x4 oacc[3];
    #pragma unroll
    for (int nt = 0; nt < 3; ++nt) oacc[nt] = (f32x4){0.f, 0.f, 0.f, 0.f};
    #pragma unroll
    for (int ks = 0; ks < 3; ++ks) {
      short8 a = *reinterpret_cast<const short8*>(&Pt[w * 16 + l16][ks * 32 + lhi * 8]);
      #pragma unroll
      for (int nt = 0; nt < 3; ++nt) {
        short8 bb = *reinterpret_cast<const short8*>(&vh[(nt * 16 + l16) * 96 + ks * 32 + lhi * 8]);
        oacc[nt] = __builtin_amdgcn_mfma_f32_16x16x32_bf16(a, bb, oacc[nt], 0, 0, 0);
      }
    }
    #pragma unroll
    for (int nt = 0; nt < 3; ++nt) {
      int d = nt * 16 + l16;
      if (d < 40) {
        #pragma unroll
        for (int r = 0; r < 4; ++r)
          XO[w * 16 + lhi * 4 + r][h * 40 + d] = f2bf(oacc[nt][r]);
      }
    }
    __syncthreads();
  }

  // --- Phase 3: out = O @ Wot^T + bo ---
  {
    f32x4 cacc[4][5];
    #pragma unroll
    for (int rt = 0; rt < 4; ++rt)
      #pragma unroll
      for (int nt = 0; nt < 5; ++nt) cacc[rt][nt] = (f32x4){0.f, 0.f, 0.f, 0.f};
    for (int ks = 0; ks < 10; ++ks) {
      short8 afrag[4];
      #pragma unroll
      for (int rt = 0; rt < 4; ++rt)
        afrag[rt] = *reinterpret_cast<const short8*>(&XO[rt * 16 + l16][ks * 32 + lhi * 8]);
      short8 bfrag[5];
      #pragma unroll
      for (int nt = 0; nt < 5; ++nt) {
        int col = w * 80 + nt * 16 + l16;
        bfrag[nt] = *reinterpret_cast<const short8*>(&wot[col * 320 + ks * 32 + lhi * 8]);
      }
      #pragma unroll
      for (int rt = 0; rt < 4; ++rt)
        #pragma unroll
        for (int nt = 0; nt < 5; ++nt)
          cacc[rt][nt] = __builtin_amdgcn_mfma_f32_16x16x32_bf16(afrag[rt], bfrag[nt], cacc[rt][nt], 0, 0, 0);
    }
    #pragma unroll
    for (int nt = 0; nt < 5; ++nt) {
      int col = w * 80 + nt * 16 + l16;
      float bias = bo[col];
      #pragma unroll
      for (int rt = 0; rt < 4; ++rt) {
        #pragma unroll
        for (int r = 0; r < 4; ++r) {
          int row = rt * 16 + lhi * 4 + r;
          out[(size_t)(b * 4096 + q0 + row) * 320 + col] = cacc[rt][nt][r] + bias;
        }
      }
    }
  }
}

extern "C" void kernel_launch(void* const* d_in, const int* in_sizes, int n_in,
                              void* d_out, int out_size, void* d_ws, size_t ws_size,
                              hipStream_t stream) {
  (void)in_sizes; (void)n_in; (void)out_size; (void)ws_size;
  const float* x       = (const float*)d_in[0];
  const float* context = (const float*)d_in[1];
  const float* Wq      = (const float*)d_in[2];
  const float* Wk      = (const float*)d_in[3];
  const float* Wv      = (const float*)d_in[4];
  const float* Wo      = (const float*)d_in[5];
  const float* bo      = (const float*)d_in[6];
  float* out = (float*)d_out;
  unsigned short* ws = (unsigned short*)d_ws;
  unsigned short* wqt = ws;                     // 102400
  unsigned short* wot = ws + 102400;            // 102400
  unsigned short* kbf = ws + 204800;            // 655360
  unsigned short* vtp = ws + 860160;            // 589824

  prep_weights<<<800, 256, 0, stream>>>(Wq, Wo, wqt, wot);
  kv_kernel<<<dim3(16, 8, 4), 256, 0, stream>>>(context, Wk, Wv, kbf, vtp);
  attn_kernel<<<dim3(64, 16), 256, 0, stream>>>(x, bo, out, wqt, wot, kbf, vtp);
}

// Round 3
// 252.749 us; speedup vs baseline: 1.5459x; 1.5459x over previous
//
#include <hip/hip_runtime.h>

typedef unsigned short u16;
using short8 = __attribute__((ext_vector_type(8))) short;
using f32x4  = __attribute__((ext_vector_type(4))) float;

#define SCALE 0.15811388300841897f  // 40^-0.5

__device__ __forceinline__ u16 f2bf(float f) {
  unsigned int u = __float_as_uint(f);
  u += 0x7fffu + ((u >> 16) & 1u);   // RNE
  return (u16)(u >> 16);
}

// ---------------- ws layout (u16 units) ----------------
// wqt [320][320]        @ 0        (102400)  Wq^T * SCALE, bf16
// wot [320][320]        @ 102400   (102400)  Wo^T, bf16
// wkt [320][768]        @ 204800   (245760)  Wk^T, bf16
// wvt [320][768]        @ 450560   (245760)  Wv^T, bf16
// kbf [16][8][80][64]   @ 696320   (655360)  K  (m pad->80, d pad->64 zeroed)
// vt  [16][8][48][96]   @ 1351680  (589824)  V^T (d pad->48 zeroed, m pad->96 zeroed)

// ============ kernel 0: LDS-tiled weight transpose + bf16 ============
__global__ void prep_transpose(const float* __restrict__ Wq, const float* __restrict__ Wo,
                               const float* __restrict__ Wk, const float* __restrict__ Wv,
                               u16* __restrict__ wqt, u16* __restrict__ wot,
                               u16* __restrict__ wkt, u16* __restrict__ wvt) {
  __shared__ float ld[64][65];
  const int bid = blockIdx.x;
  const float* src; u16* dst; int K; float scale; int tk, tn;
  if (bid < 25)       { src = Wq; dst = wqt; K = 320; scale = SCALE; tk = bid / 5;         tn = bid % 5; }
  else if (bid < 50)  { src = Wo; dst = wot; K = 320; scale = 1.f;   tk = (bid - 25) / 5;  tn = (bid - 25) % 5; }
  else if (bid < 110) { src = Wk; dst = wkt; K = 768; scale = 1.f;   tk = (bid - 50) / 5;  tn = (bid - 50) % 5; }
  else                { src = Wv; dst = wvt; K = 768; scale = 1.f;   tk = (bid - 110) / 5; tn = (bid - 110) % 5; }
  const int c = threadIdx.x & 63, r0 = threadIdx.x >> 6;
  for (int rr = r0; rr < 64; rr += 4)
    ld[rr][c] = src[(size_t)(tk * 64 + rr) * 320 + tn * 64 + c];
  __syncthreads();
  for (int rr = r0; rr < 64; rr += 4)
    dst[(size_t)(tn * 64 + rr) * K + tk * 64 + c] = f2bf(ld[c][rr] * scale);
}

// ============ kernel 1: K,V projection via MFMA ============
// grid 16 (batch), 512 threads (8 waves). Output 80 (keys,pad) x 640 (K|V cols).
__global__ __launch_bounds__(512, 1)
void kv_mfma(const float* __restrict__ ctx,
             const u16* __restrict__ wkt, const u16* __restrict__ wvt,
             u16* __restrict__ kbf, u16* __restrict__ vt) {
  const int b = blockIdx.x;
  const int tid = threadIdx.x;
  const int w = tid >> 6, l = tid & 63, l16 = l & 15, lhi = l >> 4;
  __shared__ __align__(16) u16 sctx[80][776];   // 124,160 B

  // stage ctx[b] -> bf16 LDS (rows 77..79 zero)
  for (int i = tid; i < 80 * 192; i += 512) {
    int row = i / 192, c4 = (i - row * 192) * 4;
    ushort4 u;
    if (row < 77) {
      float4 v = *reinterpret_cast<const float4*>(&ctx[(size_t)(b * 77 + row) * 768 + c4]);
      u.x = f2bf(v.x); u.y = f2bf(v.y); u.z = f2bf(v.z); u.w = f2bf(v.w);
    } else u = (ushort4){0, 0, 0, 0};
    *reinterpret_cast<ushort4*>(&sctx[row][c4]) = u;
  }
  // zero all pad regions of kbf/vt so every byte attn reads is written this call:
  // kbf d-pad cols 40..63 (every row)
  for (int i = tid; i < 8 * 80 * 3; i += 512) {
    int hm = i / 3, q = i - hm * 3;
    int h = hm / 80, m = hm - h * 80;
    *reinterpret_cast<uint4*>(&kbf[(((size_t)b * 8 + h) * 80 + m) * 64 + 40 + q * 8]) = (uint4){0, 0, 0, 0};
  }
  // vt m-pad cols 80..95 (rows 0..47)
  for (int i = tid; i < 8 * 48 * 2; i += 512) {
    int hd = i / 2, q = i - hd * 2;
    int h = hd / 48, d = hd - h * 48;
    *reinterpret_cast<uint4*>(&vt[(((size_t)b * 8 + h) * 48 + d) * 96 + 80 + q * 8]) = (uint4){0, 0, 0, 0};
  }
  // vt d-pad rows 40..47, cols 0..79
  for (int i = tid; i < 8 * 8 * 10; i += 512) {
    int h = i / 80, rem = i - h * 80;
    int d = 40 + rem / 10, q = rem - (rem / 10) * 10;
    *reinterpret_cast<uint4*>(&vt[(((size_t)b * 8 + h) * 48 + d) * 96 + q * 8]) = (uint4){0, 0, 0, 0};
  }
  __syncthreads();

  f32x4 acc[5][5];
  #pragma unroll
  for (int rt = 0; rt < 5; ++rt)
    #pragma unroll
    for (int nt = 0; nt < 5; ++nt) acc[rt][nt] = (f32x4){0.f, 0.f, 0.f, 0.f};

  const u16* wbase = (w < 4) ? (wkt + (size_t)(w * 80) * 768)
                             : (wvt + (size_t)((w - 4) * 80) * 768);
  #pragma unroll 2
  for (int ks = 0; ks < 24; ++ks) {
    short8 af[5];
    #pragma unroll
    for (int rt = 0; rt < 5; ++rt)
      af[rt] = *reinterpret_cast<const short8*>(&sctx[rt * 16 + l16][ks * 32 + lhi * 8]);
    short8 bf[5];
    #pragma unroll
    for (int nt = 0; nt < 5; ++nt)
      bf[nt] = *reinterpret_cast<const short8*>(&wbase[(size_t)(nt * 16 + l16) * 768 + ks * 32 + lhi * 8]);
    #pragma unroll
    for (int rt = 0; rt < 5; ++rt)
      #pragma unroll
      for (int nt = 0; nt < 5; ++nt)
        acc[rt][nt] = __builtin_amdgcn_mfma_f32_16x16x32_bf16(af[rt], bf[nt], acc[rt][nt], 0, 0, 0);
  }

  if (w < 4) {   // K side: kbf[b][h][m][d]
    #pragma unroll
    for (int rt = 0; rt < 5; ++rt)
      #pragma unroll
      for (int nt = 0; nt < 5; ++nt) {
        int c = w * 80 + nt * 16 + l16, h = c / 40, d = c - h * 40;
        #pragma unroll
        for (int r = 0; r < 4; ++r) {
          int m = rt * 16 + lhi * 4 + r;
          kbf[(((size_t)b * 8 + h) * 80 + m) * 64 + d] = f2bf(m < 77 ? acc[rt][nt][r] : 0.f);
        }
      }
  } else {       // V side: vt[b][h][d][m]
    #pragma unroll
    for (int rt = 0; rt < 5; ++rt)
      #pragma unroll
      for (int nt = 0; nt < 5; ++nt) {
        int c = (w - 4) * 80 + nt * 16 + l16, h = c / 40, d = c - h * 40;
        #pragma unroll
        for (int r = 0; r < 4; ++r) {
          int m = rt * 16 + lhi * 4 + r;
          vt[(((size_t)b * 8 + h) * 48 + d) * 96 + m] = f2bf(m < 77 ? acc[rt][nt][r] : 0.f);
        }
      }
  }
}

// ============ kernel 2: fused Q-GEMM + attention + out-proj ============
// grid (64 qtiles, 16 batch), 512 threads (8 waves). 64 query rows/block.
__global__ __launch_bounds__(512, 1)
void attn_kernel(const float* __restrict__ x, const float* __restrict__ bo,
                 float* __restrict__ out,
                 const u16* __restrict__ wqt, const u16* __restrict__ wot,
                 const u16* __restrict__ kbf, const u16* __restrict__ vtp) {
  const int b  = blockIdx.y;
  const int q0 = blockIdx.x * 64;
  const int tid = threadIdx.x;
  const int w   = tid >> 6;       // wave 0..7
  const int l   = tid & 63;
  const int l16 = l & 15;
  const int lhi = l >> 4;
  const int w2 = w >> 2;          // GEMM row half (0..1)
  const int w4 = w & 3;           // GEMM col quarter (0..3)

  __shared__ __align__(16) u16 Qt[64][520];      // 66,560 B (head-blocked, pad zeroed)
  __shared__ __align__(16) u16 XO[64][328];      // 41,984 B (x tile, then O tile)
  __shared__ __align__(16) u16 Pt[8][16][104];   // 26,624 B (per-wave P)

  // init: zero Qt, load x -> bf16, zero own Pt pad cols 80..95
  {
    uint4* qz = reinterpret_cast<uint4*>(&Qt[0][0]);
    for (int i = tid; i < 64 * 520 * 2 / 16; i += 512) qz[i] = (uint4){0u, 0u, 0u, 0u};
    const float4* xin = reinterpret_cast<const float4*>(x + (size_t)(b * 4096 + q0) * 320);
    for (int i = tid; i < 64 * 80; i += 512) {
      float4 v = xin[i];
      int row = i / 80, c4 = (i - row * 80) * 4;
      ushort4 u;
      u.x = f2bf(v.x); u.y = f2bf(v.y); u.z = f2bf(v.z); u.w = f2bf(v.w);
      *reinterpret_cast<ushort4*>(&XO[row][c4]) = u;
    }
    if (l < 32) {
      int r = l >> 1, q = l & 1;
      *reinterpret_cast<uint4*>(&Pt[w][r][80 + 8 * q]) = (uint4){0u, 0u, 0u, 0u};
    }
  }
  __syncthreads();

  // --- Phase 1: Q = X @ Wq^T (wave: rows 32*w2.., cols 80*w4..) ---
  {
    f32x4 qacc[2][5];
    #pragma unroll
    for (int rt = 0; rt < 2; ++rt)
      #pragma unroll
      for (int nt = 0; nt < 5; ++nt) qacc[rt][nt] = (f32x4){0.f, 0.f, 0.f, 0.f};
    #pragma unroll 2
    for (int ks = 0; ks < 10; ++ks) {
      short8 af[2];
      #pragma unroll
      for (int rt = 0; rt < 2; ++rt)
        af[rt] = *reinterpret_cast<const short8*>(&XO[w2 * 32 + rt * 16 + l16][ks * 32 + lhi * 8]);
      short8 bf[5];
      #pragma unroll
      for (int nt = 0; nt < 5; ++nt)
        bf[nt] = *reinterpret_cast<const short8*>(&wqt[(size_t)(w4 * 80 + nt * 16 + l16) * 320 + ks * 32 + lhi * 8]);
      #pragma unroll
      for (int rt = 0; rt < 2; ++rt)
        #pragma unroll
        for (int nt = 0; nt < 5; ++nt)
          qacc[rt][nt] = __builtin_amdgcn_mfma_f32_16x16x32_bf16(af[rt], bf[nt], qacc[rt][nt], 0, 0, 0);
    }
    #pragma unroll
    for (int rt = 0; rt < 2; ++rt)
      #pragma unroll
      for (int nt = 0; nt < 5; ++nt) {
        int c = w4 * 80 + nt * 16 + l16, h = c / 40, d = c - h * 40;
        int row0 = w2 * 32 + rt * 16 + lhi * 4;
        #pragma unroll
        for (int r = 0; r < 4; ++r)
          Qt[row0 + r][h * 64 + d] = f2bf(qacc[rt][nt][r]);
      }
  }
  __syncthreads();

  // --- Phase 2: attention. wave: rows 16*(w&3)..+15, heads 4*(w>>2)..+3 ---
  // Barrier discipline (R1-proven): barrier between P-write and P-read, and
  // barrier after O-write / before next head's P overwrite. All waves run the
  // same 4 iterations, so barriers are uniformly reached.
  {
    const int wq = w & 3, hg = w >> 2;
    u16* Ptw = &Pt[w][0][0];
    for (int hi = 0; hi < 4; ++hi) {
      const int h = hg * 4 + hi;
      const u16* kh = kbf + ((size_t)(b * 8 + h)) * 80 * 64;
      const u16* vh = vtp + ((size_t)(b * 8 + h)) * 48 * 96;
      // S = Q K^T
      f32x4 sacc[5];
      #pragma unroll
      for (int mt = 0; mt < 5; ++mt) sacc[mt] = (f32x4){0.f, 0.f, 0.f, 0.f};
      #pragma unroll
      for (int ks = 0; ks < 2; ++ks) {
        short8 a = *reinterpret_cast<const short8*>(&Qt[wq * 16 + l16][h * 64 + ks * 32 + lhi * 8]);
        #pragma unroll
        for (int mt = 0; mt < 5; ++mt) {
          short8 bb = *reinterpret_cast<const short8*>(&kh[(mt * 16 + l16) * 64 + ks * 32 + lhi * 8]);
          sacc[mt] = __builtin_amdgcn_mfma_f32_16x16x32_bf16(a, bb, sacc[mt], 0, 0, 0);
        }
      }
      // softmax (row = wq*16 + lhi*4 + r; keys split across l16, mt)
      #pragma unroll
      for (int r = 0; r < 4; ++r) {
        float sv[5];
        float mx = -1e30f;
        #pragma unroll
        for (int mt = 0; mt < 5; ++mt) {
          float s = sacc[mt][r];
          if (mt * 16 + l16 >= 77) s = -1e30f;
          sv[mt] = s;
          mx = fmaxf(mx, s);
        }
        mx = fmaxf(mx, __shfl_xor(mx, 1));
        mx = fmaxf(mx, __shfl_xor(mx, 2));
        mx = fmaxf(mx, __shfl_xor(mx, 4));
        mx = fmaxf(mx, __shfl_xor(mx, 8));
        float sum = 0.f;
        #pragma unroll
        for (int mt = 0; mt < 5; ++mt) { sv[mt] = __expf(sv[mt] - mx); sum += sv[mt]; }
        sum += __shfl_xor(sum, 1);
        sum += __shfl_xor(sum, 2);
        sum += __shfl_xor(sum, 4);
        sum += __shfl_xor(sum, 8);
        float rs = 1.f / sum;
        int row = lhi * 4 + r;
        #pragma unroll
        for (int mt = 0; mt < 5; ++mt)
          Ptw[row * 104 + mt * 16 + l16] = f2bf(sv[mt] * rs);
      }
      __syncthreads();   // P visible before PV reads it
      // O_h = P V
      f32x4 oacc[3];
      #pragma unroll
      for (int nt = 0; nt < 3; ++nt) oacc[nt] = (f32x4){0.f, 0.f, 0.f, 0.f};
      #pragma unroll
      for (int ks = 0; ks < 3; ++ks) {
        short8 a = *reinterpret_cast<const short8*>(&Ptw[l16 * 104 + ks * 32 + lhi * 8]);
        #pragma unroll
        for (int nt = 0; nt < 3; ++nt) {
          short8 bb = *reinterpret_cast<const short8*>(&vh[(nt * 16 + l16) * 96 + ks * 32 + lhi * 8]);
          oacc[nt] = __builtin_amdgcn_mfma_f32_16x16x32_bf16(a, bb, oacc[nt], 0, 0, 0);
        }
      }
      #pragma unroll
      for (int nt = 0; nt < 3; ++nt) {
        int d = nt * 16 + l16;
        if (d < 40) {
          #pragma unroll
          for (int r = 0; r < 4; ++r)
            XO[wq * 16 + lhi * 4 + r][h * 40 + d] = f2bf(oacc[nt][r]);
        }
      }
      __syncthreads();   // P reads done before next head overwrites P
    }
  }

  // --- Phase 3: out = O @ Wo^T + bo ---
  {
    f32x4 cacc[2][5];
    #pragma unroll
    for (int rt = 0; rt < 2; ++rt)
      #pragma unroll
      for (int nt = 0; nt < 5; ++nt) cacc[rt][nt] = (f32x4){0.f, 0.f, 0.f, 0.f};
    #pragma unroll 2
    for (int ks = 0; ks < 10; ++ks) {
      short8 af[2];
      #pragma unroll
      for (int rt = 0; rt < 2; ++rt)
        af[rt] = *reinterpret_cast<const short8*>(&XO[w2 * 32 + rt * 16 + l16][ks * 32 + lhi * 8]);
      short8 bf[5];
      #pragma unroll
      for (int nt = 0; nt < 5; ++nt)
        bf[nt] = *reinterpret_cast<const short8*>(&wot[(size_t)(w4 * 80 + nt * 16 + l16) * 320 + ks * 32 + lhi * 8]);
      #pragma unroll
      for (int rt = 0; rt < 2; ++rt)
        #pragma unroll
        for (int nt = 0; nt < 5; ++nt)
          cacc[rt][nt] = __builtin_amdgcn_mfma_f32_16x16x32_bf16(af[rt], bf[nt], cacc[rt][nt], 0, 0, 0);
    }
    #pragma unroll
    for (int nt = 0; nt < 5; ++nt) {
      int col = w4 * 80 + nt * 16 + l16;
      float bias = bo[col];
      #pragma unroll
      for (int rt = 0; rt < 2; ++rt) {
        #pragma unroll
        for (int r = 0; r < 4; ++r) {
          int row = w2 * 32 + rt * 16 + lhi * 4 + r;
          out[(size_t)(b * 4096 + q0 + row) * 320 + col] = cacc[rt][nt][r] + bias;
        }
      }
    }
  }
}

extern "C" void kernel_launch(void* const* d_in, const int* in_sizes, int n_in,
                              void* d_out, int out_size, void* d_ws, size_t ws_size,
                              hipStream_t stream) {
  (void)in_sizes; (void)n_in; (void)out_size; (void)ws_size;
  const float* x       = (const float*)d_in[0];
  const float* context = (const float*)d_in[1];
  const float* Wq      = (const float*)d_in[2];
  const float* Wk      = (const float*)d_in[3];
  const float* Wv      = (const float*)d_in[4];
  const float* Wo      = (const float*)d_in[5];
  const float* bo      = (const float*)d_in[6];
  float* out = (float*)d_out;
  u16* ws = (u16*)d_ws;
  u16* wqt = ws;                 // 102400
  u16* wot = ws + 102400;        // 102400
  u16* wkt = ws + 204800;        // 245760
  u16* wvt = ws + 450560;        // 245760
  u16* kbf = ws + 696320;        // 655360
  u16* vtp = ws + 1351680;       // 589824

  prep_transpose<<<170, 256, 0, stream>>>(Wq, Wo, Wk, Wv, wqt, wot, wkt, wvt);
  kv_mfma<<<16, 512, 0, stream>>>(context, wkt, wvt, kbf, vtp);
  attn_kernel<<<dim3(64, 16), 512, 0, stream>>>(x, bo, out, wqt, wot, kbf, vtp);
}

// Round 4
// 208.678 us; speedup vs baseline: 1.8724x; 1.2112x over previous
//
#include <hip/hip_runtime.h>

typedef unsigned short u16;
using short8 = __attribute__((ext_vector_type(8))) short;
using f32x4  = __attribute__((ext_vector_type(4))) float;

#define SCALE 0.15811388300841897f  // 40^-0.5

__device__ __forceinline__ u16 f2bf(float f) {
  unsigned int u = __float_as_uint(f);
  u += 0x7fffu + ((u >> 16) & 1u);   // RNE
  return (u16)(u >> 16);
}

// ---------------- ws layout (u16 units) ----------------
// wqt [320][320]        @ 0        (102400)  Wq^T * SCALE, bf16
// wot [320][320]        @ 102400   (102400)  Wo^T, bf16
// wkt [320][768]        @ 204800   (245760)  Wk^T, bf16
// wvt [320][768]        @ 450560   (245760)  Wv^T, bf16
// kbf [16][8][80][64]   @ 696320   (655360)  K  (m pad->80, d pad->64 zeroed)
// vt  [16][8][48][96]   @ 1351680  (589824)  V^T (d pad->48 zeroed, m pad->96 zeroed)
// qg  [65536][320]      @ 1941504  (20971520) Q bf16 (natural layout)
// slack 64 u16          @ 22913024 (zeroed by qproj; absorbs benign A-frag overrun)

// ============ kernel 0: LDS-tiled weight transpose + bf16 ============
__global__ void prep_transpose(const float* __restrict__ Wq, const float* __restrict__ Wo,
                               const float* __restrict__ Wk, const float* __restrict__ Wv,
                               u16* __restrict__ wqt, u16* __restrict__ wot,
                               u16* __restrict__ wkt, u16* __restrict__ wvt) {
  __shared__ float ld[64][65];
  const int bid = blockIdx.x;
  const float* src; u16* dst; int K; float scale; int tk, tn;
  if (bid < 25)       { src = Wq; dst = wqt; K = 320; scale = SCALE; tk = bid / 5;         tn = bid % 5; }
  else if (bid < 50)  { src = Wo; dst = wot; K = 320; scale = 1.f;   tk = (bid - 25) / 5;  tn = (bid - 25) % 5; }
  else if (bid < 110) { src = Wk; dst = wkt; K = 768; scale = 1.f;   tk = (bid - 50) / 5;  tn = (bid - 50) % 5; }
  else                { src = Wv; dst = wvt; K = 768; scale = 1.f;   tk = (bid - 110) / 5; tn = (bid - 110) % 5; }
  const int c = threadIdx.x & 63, r0 = threadIdx.x >> 6;
  for (int rr = r0; rr < 64; rr += 4)
    ld[rr][c] = src[(size_t)(tk * 64 + rr) * 320 + tn * 64 + c];
  __syncthreads();
  for (int rr = r0; rr < 64; rr += 4)
    dst[(size_t)(tn * 64 + rr) * K + tk * 64 + c] = f2bf(ld[c][rr] * scale);
}

// ============ kernel 1: K,V projection via MFMA ============
__global__ __launch_bounds__(512, 1)
void kv_mfma(const float* __restrict__ ctx,
             const u16* __restrict__ wkt, const u16* __restrict__ wvt,
             u16* __restrict__ kbf, u16* __restrict__ vt) {
  const int b = blockIdx.x;
  const int tid = threadIdx.x;
  const int w = tid >> 6, l = tid & 63, l16 = l & 15, lhi = l >> 4;
  __shared__ __align__(16) u16 sctx[80][776];

  for (int i = tid; i < 80 * 192; i += 512) {
    int row = i / 192, c4 = (i - row * 192) * 4;
    ushort4 u;
    if (row < 77) {
      float4 v = *reinterpret_cast<const float4*>(&ctx[(size_t)(b * 77 + row) * 768 + c4]);
      u.x = f2bf(v.x); u.y = f2bf(v.y); u.z = f2bf(v.z); u.w = f2bf(v.w);
    } else u = (ushort4){0, 0, 0, 0};
    *reinterpret_cast<ushort4*>(&sctx[row][c4]) = u;
  }
  // zero every pad byte attn reads
  for (int i = tid; i < 8 * 80 * 3; i += 512) {
    int hm = i / 3, q = i - hm * 3;
    int h = hm / 80, m = hm - h * 80;
    *reinterpret_cast<uint4*>(&kbf[(((size_t)b * 8 + h) * 80 + m) * 64 + 40 + q * 8]) = (uint4){0, 0, 0, 0};
  }
  for (int i = tid; i < 8 * 48 * 2; i += 512) {
    int hd = i / 2, q = i - hd * 2;
    int h = hd / 48, d = hd - h * 48;
    *reinterpret_cast<uint4*>(&vt[(((size_t)b * 8 + h) * 48 + d) * 96 + 80 + q * 8]) = (uint4){0, 0, 0, 0};
  }
  for (int i = tid; i < 8 * 8 * 10; i += 512) {
    int h = i / 80, rem = i - h * 80;
    int d = 40 + rem / 10, q = rem - (rem / 10) * 10;
    *reinterpret_cast<uint4*>(&vt[(((size_t)b * 8 + h) * 48 + d) * 96 + q * 8]) = (uint4){0, 0, 0, 0};
  }
  __syncthreads();

  f32x4 acc[5][5];
  #pragma unroll
  for (int rt = 0; rt < 5; ++rt)
    #pragma unroll
    for (int nt = 0; nt < 5; ++nt) acc[rt][nt] = (f32x4){0.f, 0.f, 0.f, 0.f};

  const u16* wbase = (w < 4) ? (wkt + (size_t)(w * 80) * 768)
                             : (wvt + (size_t)((w - 4) * 80) * 768);
  #pragma unroll 2
  for (int ks = 0; ks < 24; ++ks) {
    short8 af[5];
    #pragma unroll
    for (int rt = 0; rt < 5; ++rt)
      af[rt] = *reinterpret_cast<const short8*>(&sctx[rt * 16 + l16][ks * 32 + lhi * 8]);
    short8 bf[5];
    #pragma unroll
    for (int nt = 0; nt < 5; ++nt)
      bf[nt] = *reinterpret_cast<const short8*>(&wbase[(size_t)(nt * 16 + l16) * 768 + ks * 32 + lhi * 8]);
    #pragma unroll
    for (int rt = 0; rt < 5; ++rt)
      #pragma unroll
      for (int nt = 0; nt < 5; ++nt)
        acc[rt][nt] = __builtin_amdgcn_mfma_f32_16x16x32_bf16(af[rt], bf[nt], acc[rt][nt], 0, 0, 0);
  }

  if (w < 4) {
    #pragma unroll
    for (int rt = 0; rt < 5; ++rt)
      #pragma unroll
      for (int nt = 0; nt < 5; ++nt) {
        int c = w * 80 + nt * 16 + l16, h = c / 40, d = c - h * 40;
        #pragma unroll
        for (int r = 0; r < 4; ++r) {
          int m = rt * 16 + lhi * 4 + r;
          kbf[(((size_t)b * 8 + h) * 80 + m) * 64 + d] = f2bf(m < 77 ? acc[rt][nt][r] : 0.f);
        }
      }
  } else {
    #pragma unroll
    for (int rt = 0; rt < 5; ++rt)
      #pragma unroll
      for (int nt = 0; nt < 5; ++nt) {
        int c = (w - 4) * 80 + nt * 16 + l16, h = c / 40, d = c - h * 40;
        #pragma unroll
        for (int r = 0; r < 4; ++r) {
          int m = rt * 16 + lhi * 4 + r;
          vt[(((size_t)b * 8 + h) * 48 + d) * 96 + m] = f2bf(m < 77 ? acc[rt][nt][r] : 0.f);
        }
      }
  }
}

// ============ kernel 2: Q projection GEMM ============
// grid 1024, 256 thr (4 waves). 64 rows x 320 cols per block; wave w: cols 80w..80w+79.
__global__ __launch_bounds__(256, 3)
void qproj(const float* __restrict__ x, const u16* __restrict__ wqt,
           u16* __restrict__ qg) {
  const int tid = threadIdx.x;
  const int w = tid >> 6, l = tid & 63, l16 = l & 15, lhi = l >> 4;
  const int r0 = blockIdx.x * 64;
  __shared__ __align__(16) u16 xs[64][328];   // 41,984 B -> 3 blocks/CU

  const float4* xin = reinterpret_cast<const float4*>(x + (size_t)r0 * 320);
  for (int i = tid; i < 64 * 80; i += 256) {
    float4 v = xin[i];
    int row = i / 80, c4 = (i - row * 80) * 4;
    ushort4 u;
    u.x = f2bf(v.x); u.y = f2bf(v.y); u.z = f2bf(v.z); u.w = f2bf(v.w);
    *reinterpret_cast<ushort4*>(&xs[row][c4]) = u;
  }
  if (blockIdx.x == 1023 && tid < 64) qg[(size_t)65536 * 320 + tid] = 0;  // zero slack
  __syncthreads();

  f32x4 acc[4][5];
  #pragma unroll
  for (int rt = 0; rt < 4; ++rt)
    #pragma unroll
    for (int nt = 0; nt < 5; ++nt) acc[rt][nt] = (f32x4){0.f, 0.f, 0.f, 0.f};
  #pragma unroll 2
  for (int ks = 0; ks < 10; ++ks) {
    short8 af[4];
    #pragma unroll
    for (int rt = 0; rt < 4; ++rt)
      af[rt] = *reinterpret_cast<const short8*>(&xs[rt * 16 + l16][ks * 32 + lhi * 8]);
    #pragma unroll
    for (int nt = 0; nt < 5; ++nt) {
      short8 bf = *reinterpret_cast<const short8*>(&wqt[(size_t)(w * 80 + nt * 16 + l16) * 320 + ks * 32 + lhi * 8]);
      #pragma unroll
      for (int rt = 0; rt < 4; ++rt)
        acc[rt][nt] = __builtin_amdgcn_mfma_f32_16x16x32_bf16(af[rt], bf, acc[rt][nt], 0, 0, 0);
    }
  }
  #pragma unroll
  for (int rt = 0; rt < 4; ++rt)
    #pragma unroll
    for (int nt = 0; nt < 5; ++nt) {
      int col = w * 80 + nt * 16 + l16;
      #pragma unroll
      for (int r = 0; r < 4; ++r) {
        int row = rt * 16 + lhi * 4 + r;
        qg[(size_t)(r0 + row) * 320 + col] = f2bf(acc[rt][nt][r]);
      }
    }
}

// ============ kernel 3: attention + out-projection ============
// grid (64 qtiles, 16 b), 512 thr (8 waves), LDS 69 KB -> 2 blocks/CU.
// Phase A: wave = (16-row slice wq, 4 heads hg*4..) fully independent, no barriers.
// Phase B: out-proj GEMM from LDS O tile.
__global__ __launch_bounds__(512, 4)
void attn3(const u16* __restrict__ qg, const u16* __restrict__ kbf,
           const u16* __restrict__ vtp, const u16* __restrict__ wot,
           const float* __restrict__ bo, float* __restrict__ out) {
  const int b  = blockIdx.y;
  const int q0 = blockIdx.x * 64;
  const int tid = threadIdx.x;
  const int w   = tid >> 6;       // 0..7
  const int l   = tid & 63;
  const int l16 = l & 15;
  const int lhi = l >> 4;
  const int wq  = w & 3;          // row slice (16 rows)
  const int hg  = w >> 2;         // head group (4 heads)

  __shared__ __align__(16) u16 XO[64][328];      // 41,984 B — O tile
  __shared__ __align__(16) u16 Pt[8][16][104];   // 26,624 B — per-wave P

  // zero own Pt pad cols 80..95 (same-wave; ordered vs PV reads by the fence below)
  if (l < 32) {
    int r = l >> 1, q = l & 1;
    *reinterpret_cast<uint4*>(&Pt[w][r][80 + 8 * q]) = (uint4){0u, 0u, 0u, 0u};
  }

  // --- Phase A: attention, wave-independent ---
  for (int hi = 0; hi < 4; ++hi) {
    const int h = hg * 4 + hi;
    const u16* kh = kbf + ((size_t)(b * 8 + h)) * 80 * 64;
    const u16* vh = vtp + ((size_t)(b * 8 + h)) * 48 * 96;
    // S = Q K^T ; A-frag straight from global Q (k overrun lands on kbf zeros)
    f32x4 sacc[5];
    #pragma unroll
    for (int mt = 0; mt < 5; ++mt) sacc[mt] = (f32x4){0.f, 0.f, 0.f, 0.f};
    #pragma unroll
    for (int ks = 0; ks < 2; ++ks) {
      short8 a = *reinterpret_cast<const short8*>(
          &qg[(size_t)(b * 4096 + q0 + wq * 16 + l16) * 320 + h * 40 + ks * 32 + lhi * 8]);
      #pragma unroll
      for (int mt = 0; mt < 5; ++mt) {
        short8 bb = *reinterpret_cast<const short8*>(&kh[(mt * 16 + l16) * 64 + ks * 32 + lhi * 8]);
        sacc[mt] = __builtin_amdgcn_mfma_f32_16x16x32_bf16(a, bb, sacc[mt], 0, 0, 0);
      }
    }
    // softmax: row = lhi*4+r, keys over (mt, l16); reduce across l16 lanes
    #pragma unroll
    for (int r = 0; r < 4; ++r) {
      float sv[5];
      float mx = -1e30f;
      #pragma unroll
      for (int mt = 0; mt < 5; ++mt) {
        float s = sacc[mt][r];
        if (mt * 16 + l16 >= 77) s = -1e30f;
        sv[mt] = s;
        mx = fmaxf(mx, s);
      }
      mx = fmaxf(mx, __shfl_xor(mx, 1));
      mx = fmaxf(mx, __shfl_xor(mx, 2));
      mx = fmaxf(mx, __shfl_xor(mx, 4));
      mx = fmaxf(mx, __shfl_xor(mx, 8));
      float sum = 0.f;
      #pragma unroll
      for (int mt = 0; mt < 5; ++mt) { sv[mt] = __expf(sv[mt] - mx); sum += sv[mt]; }
      sum += __shfl_xor(sum, 1);
      sum += __shfl_xor(sum, 2);
      sum += __shfl_xor(sum, 4);
      sum += __shfl_xor(sum, 8);
      float rs = 1.f / sum;
      int row = lhi * 4 + r;
      #pragma unroll
      for (int mt = 0; mt < 5; ++mt)
        Pt[w][row][mt * 16 + l16] = f2bf(sv[mt] * rs);
    }
    // order P writes before P reads (same wave; TBAA-proof hardware fence)
    asm volatile("s_waitcnt lgkmcnt(0)" ::: "memory");
    __builtin_amdgcn_sched_barrier(0);
    // O_h = P V
    f32x4 oacc[3];
    #pragma unroll
    for (int nt = 0; nt < 3; ++nt) oacc[nt] = (f32x4){0.f, 0.f, 0.f, 0.f};
    #pragma unroll
    for (int ks = 0; ks < 3; ++ks) {
      short8 a = *reinterpret_cast<const short8*>(&Pt[w][l16][ks * 32 + lhi * 8]);
      #pragma unroll
      for (int nt = 0; nt < 3; ++nt) {
        short8 bb = *reinterpret_cast<const short8*>(&vh[(nt * 16 + l16) * 96 + ks * 32 + lhi * 8]);
        oacc[nt] = __builtin_amdgcn_mfma_f32_16x16x32_bf16(a, bb, oacc[nt], 0, 0, 0);
      }
    }
    #pragma unroll
    for (int nt = 0; nt < 3; ++nt) {
      int d = nt * 16 + l16;
      if (d < 40) {
        #pragma unroll
        for (int r = 0; r < 4; ++r)
          XO[wq * 16 + lhi * 4 + r][h * 40 + d] = f2bf(oacc[nt][r]);
      }
    }
  }
  __syncthreads();

  // --- Phase B: out = O @ Wo^T + bo (wave: rows 32*(w>>2)? no — rows 32*w2, cols 80*w4) ---
  {
    const int w2 = w >> 2, w4 = w & 3;
    f32x4 cacc[2][5];
    #pragma unroll
    for (int rt = 0; rt < 2; ++rt)
      #pragma unroll
      for (int nt = 0; nt < 5; ++nt) cacc[rt][nt] = (f32x4){0.f, 0.f, 0.f, 0.f};
    #pragma unroll 2
    for (int ks = 0; ks < 10; ++ks) {
      short8 af[2];
      #pragma unroll
      for (int rt = 0; rt < 2; ++rt)
        af[rt] = *reinterpret_cast<const short8*>(&XO[w2 * 32 + rt * 16 + l16][ks * 32 + lhi * 8]);
      #pragma unroll
      for (int nt = 0; nt < 5; ++nt) {
        short8 bf = *reinterpret_cast<const short8*>(&wot[(size_t)(w4 * 80 + nt * 16 + l16) * 320 + ks * 32 + lhi * 8]);
        #pragma unroll
        for (int rt = 0; rt < 2; ++rt)
          cacc[rt][nt] = __builtin_amdgcn_mfma_f32_16x16x32_bf16(af[rt], bf, cacc[rt][nt], 0, 0, 0);
      }
    }
    #pragma unroll
    for (int nt = 0; nt < 5; ++nt) {
      int col = w4 * 80 + nt * 16 + l16;
      float bias = bo[col];
      #pragma unroll
      for (int rt = 0; rt < 2; ++rt) {
        #pragma unroll
        for (int r = 0; r < 4; ++r) {
          int row = w2 * 32 + rt * 16 + lhi * 4 + r;
          out[(size_t)(b * 4096 + q0 + row) * 320 + col] = cacc[rt][nt][r] + bias;
        }
      }
    }
  }
}

extern "C" void kernel_launch(void* const* d_in, const int* in_sizes, int n_in,
                              void* d_out, int out_size, void* d_ws, size_t ws_size,
                              hipStream_t stream) {
  (void)in_sizes; (void)n_in; (void)out_size; (void)ws_size;
  const float* x       = (const float*)d_in[0];
  const float* context = (const float*)d_in[1];
  const float* Wq      = (const float*)d_in[2];
  const float* Wk      = (const float*)d_in[3];
  const float* Wv      = (const float*)d_in[4];
  const float* Wo      = (const float*)d_in[5];
  const float* bo      = (const float*)d_in[6];
  float* out = (float*)d_out;
  u16* ws = (u16*)d_ws;
  u16* wqt = ws;                 // 102400
  u16* wot = ws + 102400;        // 102400
  u16* wkt = ws + 204800;        // 245760
  u16* wvt = ws + 450560;        // 245760
  u16* kbf = ws + 696320;        // 655360
  u16* vtp = ws + 1351680;       // 589824
  u16* qg  = ws + 1941504;       // 20971520 + 64 slack

  prep_transpose<<<170, 256, 0, stream>>>(Wq, Wo, Wk, Wv, wqt, wot, wkt, wvt);
  kv_mfma<<<16, 512, 0, stream>>>(context, wkt, wvt, kbf, vtp);
  qproj<<<1024, 256, 0, stream>>>(x, wqt, qg);
  attn3<<<dim3(64, 16), 512, 0, stream>>>(qg, kbf, vtp, wot, bo, out);
}